// Round 1
// baseline (1101.061 us; speedup 1.0000x reference)
//
#include <hip/hip_runtime.h>

// TopKActivation: keep top-k values per row of x[B, D], zero the rest.
// One 256-thread block per row. Row elements live in registers as
// order-preserving uint32 keys; exact k-th value found by 32-step binary
// search over key space (block-reduced counts); ties broken by lowest index
// (stable top_k semantics). Single global read + single global write.

#define DCOLS 16384
#define TPB 256
#define CHUNKS (DCOLS / 4 / TPB) /* 16 float4 chunks per thread */
#define KPT (CHUNKS * 4)         /* 64 keys per thread */

__device__ __forceinline__ unsigned enc_f32(float f) {
    unsigned u = __float_as_uint(f);
    // positive: flip sign bit; negative: flip all bits -> monotonic uint order
    return u ^ ((unsigned)((int)u >> 31) | 0x80000000u);
}

__device__ __forceinline__ float dec_f32(unsigned kk) {
    // inverse of enc_f32 (bit-exact)
    unsigned u = kk ^ (0x80000000u | ~(unsigned)((int)kk >> 31));
    return __uint_as_float(u);
}

__global__ __launch_bounds__(TPB) void topk_act_kernel(
        const float* __restrict__ x, const int* __restrict__ kptr,
        float* __restrict__ out) {
    const int tid = threadIdx.x;
    const long long row = blockIdx.x;
    const float4* __restrict__ xr = (const float4*)x + row * (DCOLS / 4);
    float4* __restrict__ outr = (float4*)out + row * (DCOLS / 4);

    // totals[0..31]: per-bisection-iteration block counts (pre-zeroed so each
    // iteration needs only ONE barrier: atomicAdd -> barrier -> read).
    // totals[36], totals[37]: cntG / cntE for the tie pass.
    __shared__ int totals[40];
    __shared__ unsigned short epfx[CHUNKS * TPB]; // rare tie-rank path

    if (tid < 40) totals[tid] = 0;

    unsigned key[KPT];
#pragma unroll
    for (int j = 0; j < CHUNKS; ++j) {
        float4 v = xr[j * TPB + tid];
        key[j * 4 + 0] = enc_f32(v.x);
        key[j * 4 + 1] = enc_f32(v.y);
        key[j * 4 + 2] = enc_f32(v.z);
        key[j * 4 + 3] = enc_f32(v.w);
    }
    const int k = *kptr;
    __syncthreads(); // totals init visible before bisection atomics

    if (k >= DCOLS || k <= 0) {
        const bool keep_all = (k >= DCOLS);
#pragma unroll
        for (int j = 0; j < CHUNKS; ++j) {
            float4 o;
            o.x = keep_all ? dec_f32(key[j * 4 + 0]) : 0.0f;
            o.y = keep_all ? dec_f32(key[j * 4 + 1]) : 0.0f;
            o.z = keep_all ? dec_f32(key[j * 4 + 2]) : 0.0f;
            o.w = keep_all ? dec_f32(key[j * 4 + 3]) : 0.0f;
            outr[j * TPB + tid] = o;
        }
        return;
    }

    // Binary search for smallest t with count(key > t) < k  =>  t == k-th
    // largest key. Invariants: count(key > hi) < k, count(key >= lo) >= k.
    unsigned lo = 0u, hi = 0xFFFFFFFFu;
    int it = 0;
    while (lo < hi) {
        const unsigned mid = lo + ((hi - lo) >> 1);
        int cnt = 0;
#pragma unroll
        for (int i = 0; i < KPT; ++i) cnt += (key[i] > mid) ? 1 : 0;
#pragma unroll
        for (int off = 32; off > 0; off >>= 1) cnt += __shfl_xor(cnt, off);
        if ((tid & 63) == 0) atomicAdd(&totals[it], cnt);
        __syncthreads();
        const int f = totals[it]; // block-uniform
        if (f < k) hi = mid; else lo = mid + 1;
        ++it; // <= 32 iterations total
    }
    const unsigned ts = lo; // k-th largest key

    // Count strictly-greater and equal; r = how many equals to keep.
    int gc = 0, ec = 0;
    unsigned long long eqmask = 0ull;
#pragma unroll
    for (int i = 0; i < KPT; ++i) {
        gc += (key[i] > ts) ? 1 : 0;
        if (key[i] == ts) { ec += 1; eqmask |= (1ull << i); }
    }
    int gcs = gc, ecs = ec;
#pragma unroll
    for (int off = 32; off > 0; off >>= 1) {
        gcs += __shfl_xor(gcs, off);
        ecs += __shfl_xor(ecs, off);
    }
    if ((tid & 63) == 0) {
        atomicAdd(&totals[36], gcs);
        atomicAdd(&totals[37], ecs);
    }
    __syncthreads();
    const int cntG = totals[36];
    const int cntE = totals[37];
    const int r = k - cntG; // 1 <= r <= cntE guaranteed

    unsigned long long keepmask = ~0ull; // common case: keep all equals
    if (r != cntE) {
        // Rare path (exact fp32 ties at the threshold): rank equals by global
        // index, keep the first r. Global index of (j, tid, c) = (j*256+tid)*4+c
        // -> lexicographic in (j, tid, c) == linear in m = j*256+tid (then c).
#pragma unroll
        for (int j = 0; j < CHUNKS; ++j) {
            unsigned nib = (unsigned)((eqmask >> (j * 4)) & 0xFull);
            unsigned c4 = (nib & 1u) + ((nib >> 1) & 1u) + ((nib >> 2) & 1u) +
                          ((nib >> 3) & 1u);
            epfx[j * TPB + tid] = (unsigned short)c4;
        }
        __syncthreads();
        if (tid == 0) { // serial exclusive prefix over 4096 entries; rare path
            unsigned run = 0;
            for (int m = 0; m < CHUNKS * TPB; ++m) {
                unsigned v = epfx[m];
                epfx[m] = (unsigned short)run;
                run += v;
            }
        }
        __syncthreads();
        keepmask = 0ull;
#pragma unroll
        for (int j = 0; j < CHUNKS; ++j) {
            int base = (int)epfx[j * TPB + tid];
#pragma unroll
            for (int c = 0; c < 4; ++c) {
                if ((eqmask >> (j * 4 + c)) & 1ull) {
                    if (base < r) keepmask |= (1ull << (j * 4 + c));
                    base += 1;
                }
            }
        }
    }

    // Epilogue: decode kept values bit-exactly, zero the rest; coalesced store.
#pragma unroll
    for (int j = 0; j < CHUNKS; ++j) {
        float4 o;
#pragma unroll
        for (int c = 0; c < 4; ++c) {
            const unsigned kk = key[j * 4 + c];
            const bool keep =
                (kk > ts) || ((kk == ts) && ((keepmask >> (j * 4 + c)) & 1ull));
            ((float*)&o)[c] = keep ? dec_f32(kk) : 0.0f;
        }
        outr[j * TPB + tid] = o;
    }
}

extern "C" void kernel_launch(void* const* d_in, const int* in_sizes, int n_in,
                              void* d_out, int out_size, void* d_ws,
                              size_t ws_size, hipStream_t stream) {
    const float* x = (const float*)d_in[0];
    const int* kp = (const int*)d_in[1];
    float* out = (float*)d_out;
    const int B = in_sizes[0] / DCOLS; // 8192 rows
    topk_act_kernel<<<B, TPB, 0, stream>>>(x, kp, out);
}